// Round 1
// baseline (1334.150 us; speedup 1.0000x reference)
//
#include <hip/hip_runtime.h>

#define B_ 32
#define C_ 512
#define HW_ 3136
#define KF_ 512
#define KM_ 48
#define NCL_ 5

typedef __attribute__((ext_vector_type(8))) short short8;
typedef __attribute__((ext_vector_type(4))) float floatx4;

__device__ __forceinline__ unsigned short f2bf(float f) {
    union { float f; unsigned u; } v; v.f = f;
    unsigned r = v.u + 0x7FFFu + ((v.u >> 16) & 1u);
    return (unsigned short)(r >> 16);
}
__device__ __forceinline__ float bf2f(unsigned short u) {
    union { unsigned u; float f; } v; v.u = ((unsigned)u) << 16;
    return v.f;
}

// ---- K0: normalize conv weights -> bf16 wn; clutter -> ck (clip + L1 norm)
__global__ __launch_bounds__(64) void prep_kernel(const float* __restrict__ w,
                                                  const float* __restrict__ cl,
                                                  unsigned short* __restrict__ wn,
                                                  float* __restrict__ ck) {
    int bid = blockIdx.x, t = threadIdx.x;
    if (bid < KF_) {
        const float* row = w + (size_t)bid * C_;
        float ss = 0.f;
        float x[8];
#pragma unroll
        for (int j = 0; j < 8; ++j) { x[j] = row[t * 8 + j]; ss += x[j] * x[j]; }
        for (int m = 32; m >= 1; m >>= 1) ss += __shfl_xor(ss, m);
        float inv = 1.f / sqrtf(ss);
#pragma unroll
        for (int j = 0; j < 8; ++j) wn[(size_t)bid * C_ + t * 8 + j] = f2bf(x[j] * inv);
    } else {
        int n = bid - KF_;
        if (n >= NCL_) return;
        const float* row = cl + (size_t)n * KF_;
        float s = 0.f;
        float v[8];
#pragma unroll
        for (int j = 0; j < 8; ++j) {
            float x = row[t * 8 + j];
            x = fminf(fmaxf(x, 0.f), 1.f);
            v[j] = x; s += x;
        }
        for (int m = 32; m >= 1; m >>= 1) s += __shfl_xor(s, m);
        float inv = 1.f / fmaxf(s, 1e-12f);
#pragma unroll
        for (int j = 0; j < 8; ++j) ck[(size_t)n * KF_ + t * 8 + j] = v[j] * inv;
    }
}

// ---- K1: per-pixel inverse L2 norm of vgg over C
__global__ __launch_bounds__(256) void xnorm_kernel(const float* __restrict__ vgg,
                                                    float* __restrict__ invn) {
    int p = blockIdx.x * 256 + threadIdx.x;
    int b = blockIdx.y;
    if (p >= HW_) return;
    const float* base = vgg + (size_t)b * C_ * HW_ + p;
    float ss = 0.f;
    for (int c = 0; c < C_; ++c) { float x = base[(size_t)c * HW_]; ss += x * x; }
    float n = sqrtf(ss);
    invn[(size_t)b * HW_ + p] = (n == 0.f) ? 1.f : 1.f / n;
}

// ---- K2: cos GEMM (MFMA bf16) + act = exp(30 cos)*(cos>0), store bf16
__global__ __launch_bounds__(256) void cosact_kernel(const float* __restrict__ vgg,
                                                     const unsigned short* __restrict__ wn,
                                                     const float* __restrict__ invn,
                                                     unsigned short* __restrict__ act) {
    int kt = blockIdx.x, ht = blockIdx.y, b = blockIdx.z;
    int tid = threadIdx.x;
    int lane = tid & 63, wid = tid >> 6;
    int wr = wid >> 1, wc = wid & 1;
    __shared__ __align__(16) unsigned short lds_a[64][64];  // [kfilter][c] xor-swizzled
    __shared__ __align__(16) unsigned short lds_b[64][64];  // [hw][c] xor-swizzled

    floatx4 acc[2][2] = {};

    int hw_l = tid & 63;
    float inv = invn[(size_t)b * HW_ + ht * 64 + hw_l];
    const float* vbase = vgg + (size_t)b * C_ * HW_ + ht * 64 + hw_l;

    for (int ct = 0; ct < 8; ++ct) {
        __syncthreads();
        // stage A: wn tile 64k x 64c (bf16), 2 chunks of 8 per thread
#pragma unroll
        for (int j = 0; j < 2; ++j) {
            int chunk = tid + j * 256;
            int k_l = chunk >> 3, cg = chunk & 7;
            short8 v = *(const short8*)(wn + (size_t)(kt * 64 + k_l) * C_ + ct * 64 + cg * 8);
            *(short8*)&lds_a[k_l][(cg ^ (k_l & 7)) * 8] = v;
        }
        // stage B: xn tile 64c x 64hw (fp32 -> bf16), transposed to [hw][c]
#pragma unroll
        for (int j = 0; j < 2; ++j) {
            int cgrp = (tid >> 6) + j * 4;
            short8 pv;
#pragma unroll
            for (int jj = 0; jj < 8; ++jj) {
                float x = vbase[(size_t)(ct * 64 + cgrp * 8 + jj) * HW_];
                pv[jj] = (short)f2bf(x * inv);
            }
            *(short8*)&lds_b[hw_l][(cgrp ^ (hw_l & 7)) * 8] = pv;
        }
        __syncthreads();
#pragma unroll
        for (int ks = 0; ks < 2; ++ks) {
            int cq = ks * 4 + (lane >> 4);
            short8 a[2], bb[2];
#pragma unroll
            for (int mi = 0; mi < 2; ++mi) {
                int row = wr * 32 + mi * 16 + (lane & 15);
                a[mi] = *(const short8*)&lds_a[row][(cq ^ (row & 7)) * 8];
            }
#pragma unroll
            for (int ni = 0; ni < 2; ++ni) {
                int row = wc * 32 + ni * 16 + (lane & 15);
                bb[ni] = *(const short8*)&lds_b[row][(cq ^ (row & 7)) * 8];
            }
#pragma unroll
            for (int mi = 0; mi < 2; ++mi)
#pragma unroll
                for (int ni = 0; ni < 2; ++ni)
                    acc[mi][ni] = __builtin_amdgcn_mfma_f32_16x16x32_bf16(
                        a[mi], bb[ni], acc[mi][ni], 0, 0, 0);
        }
    }
#pragma unroll
    for (int mi = 0; mi < 2; ++mi)
#pragma unroll
        for (int ni = 0; ni < 2; ++ni)
#pragma unroll
            for (int r = 0; r < 4; ++r) {
                int kg = kt * 64 + wr * 32 + mi * 16 + (lane >> 4) * 4 + r;
                int hg = ht * 64 + wc * 32 + ni * 16 + (lane & 15);
                float cv = acc[mi][ni][r];
                float av = cv > 0.f ? expf(30.f * cv) : 0.f;
                act[((size_t)b * KF_ + kg) * HW_ + hg] = f2bf(av);
            }
}

// ---- K3: background[b,p] = max_n log(0.6 * sum_k act*ck + 1e-10)
__global__ __launch_bounds__(256) void bg_kernel(const unsigned short* __restrict__ act,
                                                 const float* __restrict__ ck,
                                                 float* __restrict__ bgout) {
    __shared__ float ckl[NCL_ * KF_];
    int tid = threadIdx.x;
    for (int i = tid; i < NCL_ * KF_; i += 256) ckl[i] = ck[i];
    __syncthreads();
    int p = blockIdx.x * 256 + tid;
    int b = blockIdx.y;
    if (p >= HW_) return;
    float acc[NCL_] = {0.f, 0.f, 0.f, 0.f, 0.f};
    const unsigned short* abase = act + (size_t)b * KF_ * HW_ + p;
    for (int k = 0; k < KF_; ++k) {
        float a = bf2f(abase[(size_t)k * HW_]);
#pragma unroll
        for (int n = 0; n < NCL_; ++n) acc[n] += a * ckl[n * KF_ + k];
    }
    float m = -1e30f;
#pragma unroll
    for (int n = 0; n < NCL_; ++n) m = fmaxf(m, logf(acc[n] * 0.6f + 1e-10f));
    bgout[(size_t)b * HW_ + p] = m;
}

// ---- K4: fg GEMM + mm L1-norm + max(fg_log, background) + reduce over pixels
__global__ __launch_bounds__(256) void fg_kernel(const unsigned short* __restrict__ act,
                                                 const float* __restrict__ mm,
                                                 const float* __restrict__ bgin,
                                                 float* __restrict__ pm) {
    // grid.x = 98 p-tiles of 32, grid.y = 4 m-chunks of 12
    __shared__ __align__(16) unsigned short lact[8][32 * 32];  // [kk][b][p'] swizzled
    int tid = threadIdx.x;
    int p_l = tid & 31;
    int role = tid >> 5;     // 0..7
    int bh = role & 3;       // 4 groups of 8 b
    int mh = role >> 2;      // 2 groups of 6 m
    int p0 = blockIdx.x * 32;
    int m0 = blockIdx.y * 12 + mh * 6;
    int b0 = bh * 8;
    size_t pg = p0 + p_l;

    float accf[6][8] = {};
    float csum[6] = {};

    int sb = tid >> 3;       // staging: b row 0..31
    int spg = tid & 7;       // staging: p group (4-wide)
    typedef __attribute__((ext_vector_type(4))) short short4v;

    for (int k0 = 0; k0 < KF_; k0 += 8) {
        __syncthreads();
#pragma unroll
        for (int kk = 0; kk < 8; ++kk) {
            short4v v = *(const short4v*)(act + ((size_t)sb * KF_ + k0 + kk) * HW_ + p0 + spg * 4);
            *(short4v*)&lact[kk][sb * 32 + (spg ^ (sb & 7)) * 4] = v;
        }
        __syncthreads();
#pragma unroll
        for (int kk = 0; kk < 8; ++kk) {
            int k = k0 + kk;
            float mv[6];
#pragma unroll
            for (int mi = 0; mi < 6; ++mi) {
                float x = mm[((size_t)(m0 + mi) * KF_ + k) * HW_ + pg];
                x = fminf(fmaxf(x, 0.f), 1.f);
                mv[mi] = x; csum[mi] += x;
            }
#pragma unroll
            for (int bb = 0; bb < 8; ++bb) {
                int bidx = b0 + bb;
                float a = bf2f(lact[kk][bidx * 32 + (p_l ^ ((bidx & 7) << 2))]);
#pragma unroll
                for (int mi = 0; mi < 6; ++mi) accf[mi][bb] += a * mv[mi];
            }
        }
    }

    float invn[6];
#pragma unroll
    for (int mi = 0; mi < 6; ++mi) invn[mi] = 1.f / fmaxf(csum[mi], 1e-12f);
    float bgv[8];
#pragma unroll
    for (int bb = 0; bb < 8; ++bb) bgv[bb] = bgin[(size_t)(b0 + bb) * HW_ + pg];

#pragma unroll
    for (int mi = 0; mi < 6; ++mi)
#pragma unroll
        for (int bb = 0; bb < 8; ++bb) {
            float v = fmaxf(logf(accf[mi][bb] * invn[mi] * 0.4f + 1e-10f), bgv[bb]);
            for (int s = 16; s >= 1; s >>= 1) v += __shfl_xor(v, s);
            if (p_l == 0) atomicAdd(&pm[(size_t)(b0 + bb) * KM_ + m0 + mi], v);
        }
}

// ---- K5: scores -> mix_likeli -> softmax
__global__ __launch_bounds__(64) void final_kernel(const float* __restrict__ pm,
                                                   float* __restrict__ out_soft,
                                                   float* __restrict__ out_ml) {
    int b = threadIdx.x;
    if (b >= B_) return;
    float ml[12];
#pragma unroll
    for (int c = 0; c < 12; ++c) {
        float s = -1e30f;
#pragma unroll
        for (int j = 0; j < 4; ++j) s = fmaxf(s, pm[(size_t)b * KM_ + c * 4 + j]);
        ml[c] = s / (float)HW_;
    }
    float z[12], zs = 0.f;
#pragma unroll
    for (int c = 0; c < 12; ++c) {
        float e = fminf(fmaxf(ml[c] * 2.f, -88.7f), 88.7f);
        z[c] = expf(e); zs += z[c];
    }
#pragma unroll
    for (int c = 0; c < 12; ++c) {
        out_soft[(size_t)b * 12 + c] = z[c] / zs;
        out_ml[(size_t)b * 12 + c] = ml[c];
    }
}

extern "C" void kernel_launch(void* const* d_in, const int* in_sizes, int n_in,
                              void* d_out, int out_size, void* d_ws, size_t ws_size,
                              hipStream_t stream) {
    const float* vgg = (const float*)d_in[0];
    const float* cw  = (const float*)d_in[1];
    const float* mmp = (const float*)d_in[2];
    const float* cl  = (const float*)d_in[3];
    float* out = (float*)d_out;
    char* ws = (char*)d_ws;

    unsigned short* wn = (unsigned short*)(ws);            // 512*512*2 = 524288
    float* ck          = (float*)(ws + 524288);            // 5*512*4  = 10240
    float* invn        = (float*)(ws + 534528);            // 32*3136*4 = 401408
    float* bg          = (float*)(ws + 935936);            // 32*3136*4 = 401408
    float* pm          = (float*)(ws + 1337344);           // 32*48*4 = 6144

    // act (bf16) lives temporarily in the d_out vgg region; vgg copied in last.
    unsigned short* act = (unsigned short*)(out + 384);

    hipMemsetAsync(pm, 0, (size_t)B_ * KM_ * sizeof(float), stream);
    prep_kernel<<<dim3(KF_ + NCL_), dim3(64), 0, stream>>>(cw, cl, wn, ck);
    xnorm_kernel<<<dim3(13, 32), dim3(256), 0, stream>>>(vgg, invn);
    cosact_kernel<<<dim3(8, 49, 32), dim3(256), 0, stream>>>(vgg, wn, invn, act);
    bg_kernel<<<dim3(13, 32), dim3(256), 0, stream>>>(act, ck, bg);
    fg_kernel<<<dim3(98, 4), dim3(256), 0, stream>>>(act, mmp, bg, pm);
    final_kernel<<<1, 64, 0, stream>>>(pm, out, out + 384 + (size_t)B_ * C_ * HW_);
    // Finally overwrite the act region with the required vgg_feat passthrough.
    hipMemcpyAsync(out + 384, vgg, (size_t)B_ * C_ * HW_ * sizeof(float),
                   hipMemcpyDeviceToDevice, stream);
}

// Round 2
// 472.206 us; speedup vs baseline: 2.8254x; 2.8254x over previous
//
#include <hip/hip_runtime.h>

#define B_ 32
#define C_ 512
#define HW_ 3136
#define KF_ 512
#define KM_ 48
#define NCL_ 5

typedef __attribute__((ext_vector_type(8))) short short8;
typedef __attribute__((ext_vector_type(4))) short short4v;
typedef __attribute__((ext_vector_type(4))) float floatx4;

__device__ __forceinline__ unsigned short f2bf(float f) {
    union { float f; unsigned u; } v; v.f = f;
    unsigned r = v.u + 0x7FFFu + ((v.u >> 16) & 1u);
    return (unsigned short)(r >> 16);
}
__device__ __forceinline__ float bf2f(unsigned short u) {
    union { unsigned u; float f; } v; v.u = ((unsigned)u) << 16;
    return v.f;
}

// ---- K0: normalize conv weights -> bf16 wn; clutter -> ck (clip + L1 norm)
__global__ __launch_bounds__(64) void prep_kernel(const float* __restrict__ w,
                                                  const float* __restrict__ cl,
                                                  unsigned short* __restrict__ wn,
                                                  float* __restrict__ ck) {
    int bid = blockIdx.x, t = threadIdx.x;
    if (bid < KF_) {
        const float* row = w + (size_t)bid * C_;
        float ss = 0.f;
        float x[8];
#pragma unroll
        for (int j = 0; j < 8; ++j) { x[j] = row[t * 8 + j]; ss += x[j] * x[j]; }
        for (int m = 32; m >= 1; m >>= 1) ss += __shfl_xor(ss, m);
        float inv = 1.f / sqrtf(ss);
#pragma unroll
        for (int j = 0; j < 8; ++j) wn[(size_t)bid * C_ + t * 8 + j] = f2bf(x[j] * inv);
    } else {
        int n = bid - KF_;
        if (n >= NCL_) return;
        const float* row = cl + (size_t)n * KF_;
        float s = 0.f;
        float v[8];
#pragma unroll
        for (int j = 0; j < 8; ++j) {
            float x = row[t * 8 + j];
            x = fminf(fmaxf(x, 0.f), 1.f);
            v[j] = x; s += x;
        }
        for (int m = 32; m >= 1; m >>= 1) s += __shfl_xor(s, m);
        float inv = 1.f / fmaxf(s, 1e-12f);
#pragma unroll
        for (int j = 0; j < 8; ++j) ck[(size_t)n * KF_ + t * 8 + j] = v[j] * inv;
    }
}

// ---- K2: fused xnorm + cos GEMM + act, writes act_t[b][p][k] (k contiguous)
//      optional vgg passthrough write (fused copy).
// grid (49 ht, 32 b), 512 threads.
__global__ __launch_bounds__(512, 4) void cosact_kernel(const float* __restrict__ vgg,
                                                        const unsigned short* __restrict__ wn,
                                                        unsigned short* __restrict__ act,
                                                        float* __restrict__ out_vgg,
                                                        int write_vgg) {
    int ht = blockIdx.x, b = blockIdx.y;
    int tid = threadIdx.x;
    int lane = tid & 63, wid = tid >> 6;
    int wr = wid & 1, wc = wid >> 1;  // wr: k-half (32), wc: px quarter (16)

    __shared__ __align__(16) unsigned short xn[64 * 520];   // [px][c], row 1040B (bank-spread)
    __shared__ __align__(16) unsigned short wnl[64 * 72];   // [k][c],  row 144B
    __shared__ float ssp[8][64];
    __shared__ float inv_s[64];

    int px = tid & 63;
    int cq = tid >> 6;
    const float* vcol = vgg + (size_t)b * C_ * HW_ + (size_t)ht * 64 + px;
    float* ovcol = out_vgg + (size_t)b * C_ * HW_ + (size_t)ht * 64 + px;

    // phase 1: sum-of-squares + raw bf16 into LDS (+ optional vgg copy)
    float ss = 0.f;
#pragma unroll
    for (int j = 0; j < 16; ++j) {
        int c0 = cq * 64 + j * 4;
        float x0 = vcol[(size_t)(c0 + 0) * HW_];
        float x1 = vcol[(size_t)(c0 + 1) * HW_];
        float x2 = vcol[(size_t)(c0 + 2) * HW_];
        float x3 = vcol[(size_t)(c0 + 3) * HW_];
        ss += x0 * x0 + x1 * x1 + x2 * x2 + x3 * x3;
        short4v pk;
        pk[0] = (short)f2bf(x0); pk[1] = (short)f2bf(x1);
        pk[2] = (short)f2bf(x2); pk[3] = (short)f2bf(x3);
        *(short4v*)&xn[px * 520 + c0] = pk;
        if (write_vgg) {
            ovcol[(size_t)(c0 + 0) * HW_] = x0;
            ovcol[(size_t)(c0 + 1) * HW_] = x1;
            ovcol[(size_t)(c0 + 2) * HW_] = x2;
            ovcol[(size_t)(c0 + 3) * HW_] = x3;
        }
    }
    ssp[cq][px] = ss;
    __syncthreads();
    if (tid < 64) {
        float s = 0.f;
#pragma unroll
        for (int q = 0; q < 8; ++q) s += ssp[q][tid];
        float n = sqrtf(s);
        inv_s[tid] = (n == 0.f) ? 1.f : 1.f / n;
    }
    __syncthreads();

    int pxc = wc * 16 + (lane & 15);          // this lane's output pixel (col)
    float inv_px = inv_s[pxc];

    // wn staging assignment
    int wk = tid >> 3, wcg = tid & 7;
    short8 wreg = *(const short8*)(wn + (size_t)wk * C_ + wcg * 8);  // kt=0, ct=0

    unsigned short* actp = act + ((size_t)b * HW_ + (size_t)ht * 64 + pxc) * KF_;

    for (int kt = 0; kt < 8; ++kt) {
        floatx4 acc0 = {}, acc1 = {};
        for (int ct = 0; ct < 8; ++ct) {
            __syncthreads();
            *(short8*)&wnl[wk * 72 + wcg * 8] = wreg;
            int nct = ct + 1, nkt = kt;
            if (nct == 8) { nct = 0; nkt = kt + 1; }
            if (nkt < 8)
                wreg = *(const short8*)(wn + (size_t)(nkt * 64 + wk) * C_ + nct * 64 + wcg * 8);
            __syncthreads();
#pragma unroll
            for (int ks = 0; ks < 2; ++ks) {
                short8 bfr = *(const short8*)&xn[pxc * 520 + ct * 64 + ks * 32 + (lane >> 4) * 8];
                short8 af0 = *(const short8*)&wnl[(wr * 32 + 0 + (lane & 15)) * 72 + ks * 32 + (lane >> 4) * 8];
                short8 af1 = *(const short8*)&wnl[(wr * 32 + 16 + (lane & 15)) * 72 + ks * 32 + (lane >> 4) * 8];
                acc0 = __builtin_amdgcn_mfma_f32_16x16x32_bf16(af0, bfr, acc0, 0, 0, 0);
                acc1 = __builtin_amdgcn_mfma_f32_16x16x32_bf16(af1, bfr, acc1, 0, 0, 0);
            }
        }
        // epilogue for this kt: 2 packed b64 stores (k-contiguous)
#pragma unroll
        for (int mi = 0; mi < 2; ++mi) {
            floatx4 a = mi ? acc1 : acc0;
            short4v pk;
#pragma unroll
            for (int r = 0; r < 4; ++r) {
                float cv = a[r] * inv_px;
                float av = cv > 0.f ? expf(30.f * cv) : 0.f;
                pk[r] = (short)f2bf(av);
            }
            int kbase = kt * 64 + wr * 32 + mi * 16 + (lane >> 4) * 4;
            *(short4v*)(actp + kbase) = pk;
        }
    }
}

// ---- K3: background[b,p] = max_n log(0.6 * sum_k act*ck + 1e-10); act_t layout
__global__ __launch_bounds__(256) void bg_kernel(const unsigned short* __restrict__ act,
                                                 const float* __restrict__ ck,
                                                 float* __restrict__ bgout) {
    __shared__ float ckl[NCL_ * KF_];
    int tid = threadIdx.x;
    for (int i = tid; i < NCL_ * KF_; i += 256) ckl[i] = ck[i];
    __syncthreads();
    int p = blockIdx.x * 256 + tid;
    int b = blockIdx.y;
    if (p >= HW_) return;
    const unsigned short* row = act + ((size_t)b * HW_ + p) * KF_;
    float acc[NCL_] = {0.f, 0.f, 0.f, 0.f, 0.f};
    for (int k8 = 0; k8 < KF_ / 8; ++k8) {
        short8 v = *(const short8*)(row + k8 * 8);
#pragma unroll
        for (int j = 0; j < 8; ++j) {
            float a = bf2f((unsigned short)v[j]);
#pragma unroll
            for (int n = 0; n < NCL_; ++n) acc[n] += a * ckl[n * KF_ + k8 * 8 + j];
        }
    }
    float m = -1e30f;
#pragma unroll
    for (int n = 0; n < NCL_; ++n) m = fmaxf(m, logf(acc[n] * 0.6f + 1e-10f));
    bgout[(size_t)b * HW_ + p] = m;
}

// ---- K4: per-pixel batched MFMA GEMM fg = act x mm + epilogue reduce
// grid (196 p-tiles of 16, 3 m-tiles of 16), 512 threads (8 waves, 2 px each).
__global__ __launch_bounds__(512, 4) void fg_kernel(const unsigned short* __restrict__ act,
                                                    const float* __restrict__ mm,
                                                    const float* __restrict__ bgin,
                                                    float* __restrict__ pm) {
    int p0 = blockIdx.x * 16;
    int mt = blockIdx.y;
    int tid = threadIdx.x;
    int lane = tid & 63, wid = tid >> 6;

    // LDS: actl[kg4][p16][b32][8k] rows padded: p-stride 264 shorts (528B), kg-stride 4224 shorts
    //      mml [kg4][p16][m16][8k] p-stride 136 shorts (272B), kg-stride 2176 shorts
    __shared__ __align__(16) unsigned short actl[4 * 4224];
    __shared__ __align__(16) unsigned short mml[4 * 2176];
    __shared__ float csum_s[16 * 16];  // [m][p]
    __shared__ float pms[16 * 32];     // [m][b]
    __shared__ float bgs[32 * 16];     // [b][p]

    if (tid < 256) csum_s[tid] = 0.f;
    pms[tid] = 0.f;
    {
        int bb = tid >> 4, pp = tid & 15;
        bgs[tid] = bgin[(size_t)bb * HW_ + p0 + pp];
    }

    // staging maps
    int akg = tid & 3, ap = (tid >> 2) & 15, ab0 = tid >> 6;            // act
    int mmm = tid >> 5, mkq = (tid >> 2) & 7, mpq = tid & 3;            // mm
    const unsigned short* abase = act + ((size_t)0 * HW_) ;             // computed per j
    const float* mbase = mm + ((size_t)(mt * 16 + mmm) * KF_ + mkq * 4) * HW_ + p0 + mpq * 4;

    // fragment LDS pointers (constant across chunks)
    const short8* fA[2];
    const short8* fB[2][2];
#pragma unroll
    for (int e = 0; e < 2; ++e) {
        int pp = wid * 2 + e;
        fA[e] = (const short8*)&mml[(lane >> 4) * 2176 + pp * 136 + (lane & 15) * 8];
#pragma unroll
        for (int bf = 0; bf < 2; ++bf)
            fB[e][bf] = (const short8*)&actl[(lane >> 4) * 4224 + pp * 264 + (bf * 16 + (lane & 15)) * 8];
    }

    floatx4 acc[2][2] = {};
    float csr[4] = {};

    short8 areg[4];
    floatx4 mreg[4];
#pragma unroll
    for (int j = 0; j < 4; ++j)
        areg[j] = *(const short8*)(act + ((size_t)(ab0 + j * 8) * HW_ + p0 + ap) * KF_ + akg * 8);
#pragma unroll
    for (int kk = 0; kk < 4; ++kk)
        mreg[kk] = *(const floatx4*)(mbase + (size_t)kk * HW_);

    for (int ch = 0; ch < 16; ++ch) {
        __syncthreads();
        // write staged regs to LDS
#pragma unroll
        for (int j = 0; j < 4; ++j)
            *(short8*)&actl[akg * 4224 + ap * 264 + (ab0 + j * 8) * 8] = areg[j];
#pragma unroll
        for (int i = 0; i < 4; ++i) {
            float c0 = fminf(fmaxf(mreg[0][i], 0.f), 1.f);
            float c1 = fminf(fmaxf(mreg[1][i], 0.f), 1.f);
            float c2 = fminf(fmaxf(mreg[2][i], 0.f), 1.f);
            float c3 = fminf(fmaxf(mreg[3][i], 0.f), 1.f);
            csr[i] += c0 + c1 + c2 + c3;
            short4v pk;
            pk[0] = (short)f2bf(c0); pk[1] = (short)f2bf(c1);
            pk[2] = (short)f2bf(c2); pk[3] = (short)f2bf(c3);
            *(short4v*)&mml[(mkq >> 1) * 2176 + (mpq * 4 + i) * 136 + mmm * 8 + (mkq & 1) * 4] = pk;
        }
        // prefetch next chunk
        if (ch < 15) {
            int k0 = (ch + 1) * 32;
#pragma unroll
            for (int j = 0; j < 4; ++j)
                areg[j] = *(const short8*)(act + ((size_t)(ab0 + j * 8) * HW_ + p0 + ap) * KF_ + k0 + akg * 8);
#pragma unroll
            for (int kk = 0; kk < 4; ++kk)
                mreg[kk] = *(const floatx4*)(mbase + (size_t)(k0 + kk) * HW_);
        }
        __syncthreads();
        // compute
#pragma unroll
        for (int e = 0; e < 2; ++e) {
            short8 af = *fA[e];
            short8 b0 = *fB[e][0];
            short8 b1 = *fB[e][1];
            acc[e][0] = __builtin_amdgcn_mfma_f32_16x16x32_bf16(af, b0, acc[e][0], 0, 0, 0);
            acc[e][1] = __builtin_amdgcn_mfma_f32_16x16x32_bf16(af, b1, acc[e][1], 0, 0, 0);
        }
    }

    // csum reduce (fp32, pre-bf16 clip values)
#pragma unroll
    for (int i = 0; i < 4; ++i)
        atomicAdd(&csum_s[mmm * 16 + mpq * 4 + i], csr[i]);
    __syncthreads();

    // epilogue: log, max with bg, accumulate per (m,b)
#pragma unroll
    for (int e = 0; e < 2; ++e) {
        int pp = wid * 2 + e;
#pragma unroll
        for (int bf = 0; bf < 2; ++bf) {
            int bcol = bf * 16 + (lane & 15);
            float bgv = bgs[bcol * 16 + pp];
#pragma unroll
            for (int r = 0; r < 4; ++r) {
                int m = (lane >> 4) * 4 + r;
                float invn = 1.f / fmaxf(csum_s[m * 16 + pp], 1e-12f);
                float v = fmaxf(logf(acc[e][bf][r] * invn * 0.4f + 1e-10f), bgv);
                atomicAdd(&pms[m * 32 + bcol], v);
            }
        }
    }
    __syncthreads();
    {
        int m = tid >> 5, bcol = tid & 31;
        atomicAdd(&pm[(size_t)bcol * KM_ + mt * 16 + m], pms[m * 32 + bcol]);
    }
}

// ---- K5: scores -> mix_likeli -> softmax
__global__ __launch_bounds__(64) void final_kernel(const float* __restrict__ pm,
                                                   float* __restrict__ out_soft,
                                                   float* __restrict__ out_ml) {
    int b = threadIdx.x;
    if (b >= B_) return;
    float ml[12];
#pragma unroll
    for (int c = 0; c < 12; ++c) {
        float s = -1e30f;
#pragma unroll
        for (int j = 0; j < 4; ++j) s = fmaxf(s, pm[(size_t)b * KM_ + c * 4 + j]);
        ml[c] = s / (float)HW_;
    }
    float z[12], zs = 0.f;
#pragma unroll
    for (int c = 0; c < 12; ++c) {
        float e = fminf(fmaxf(ml[c] * 2.f, -88.7f), 88.7f);
        z[c] = expf(e); zs += z[c];
    }
#pragma unroll
    for (int c = 0; c < 12; ++c) {
        out_soft[(size_t)b * 12 + c] = z[c] / zs;
        out_ml[(size_t)b * 12 + c] = ml[c];
    }
}

extern "C" void kernel_launch(void* const* d_in, const int* in_sizes, int n_in,
                              void* d_out, int out_size, void* d_ws, size_t ws_size,
                              hipStream_t stream) {
    const float* vgg = (const float*)d_in[0];
    const float* cw  = (const float*)d_in[1];
    const float* mmp = (const float*)d_in[2];
    const float* cl  = (const float*)d_in[3];
    float* out = (float*)d_out;
    char* ws = (char*)d_ws;

    unsigned short* wn = (unsigned short*)(ws);            // 524288 B
    float* ck          = (float*)(ws + 524288);            // 10240 B
    float* bg          = (float*)(ws + 534528);            // 401408 B
    float* pm          = (float*)(ws + 935936);            // 6144 B
    const size_t ACT_OFF = 942080;
    const size_t ACT_BYTES = (size_t)B_ * HW_ * KF_ * 2;   // 102,760,448

    int big_ws = (ws_size >= ACT_OFF + ACT_BYTES) ? 1 : 0;
    unsigned short* act = big_ws ? (unsigned short*)(ws + ACT_OFF)
                                 : (unsigned short*)(out + 384);

    hipMemsetAsync(pm, 0, (size_t)B_ * KM_ * sizeof(float), stream);
    prep_kernel<<<dim3(KF_ + NCL_), dim3(64), 0, stream>>>(cw, cl, wn, ck);
    cosact_kernel<<<dim3(49, 32), dim3(512), 0, stream>>>(vgg, wn, act, out + 384, big_ws);
    bg_kernel<<<dim3(13, 32), dim3(256), 0, stream>>>(act, ck, bg);
    fg_kernel<<<dim3(196, 3), dim3(512), 0, stream>>>(act, mmp, bg, pm);
    final_kernel<<<1, 64, 0, stream>>>(pm, out, out + 384 + (size_t)B_ * C_ * HW_);
    if (!big_ws)
        hipMemcpyAsync(out + 384, vgg, (size_t)B_ * C_ * HW_ * sizeof(float),
                       hipMemcpyDeviceToDevice, stream);
}